// Round 16
// baseline (251.155 us; speedup 1.0000x reference)
//
#include <hip/hip_runtime.h>

#define C_IN   32
#define C_OUT  32
#define K_VOL  27
#define M_EDGE 250000
#define N_ROWS 500000
#define E_TOT  (K_VOL * M_EDGE)          // 6,750,000 edges

#define NT        (N_ROWS / 16)          // 31250 row-tiles of 16 rows
#define NREG      977                    // sort regions of 32 tiles (512 rows)
#define BPB       16                     // fill blocks per k
#define CHUNK     (M_EDGE / BPB)         // 15625 edges per (k,blk) segment
#define OSTRIDE   (NREG + 1)             // 978 offsets per segment
#define NSEG      (K_VOL * BPB)          // 432 private segments
#define NLISTS    512                    // per-(tile,row) lists in conv
#define CAPL      16                     // list capacity: P(Pois(0.5)>16) ~ 1e-19
#define LSTRIDE   17                     // pad stride: 17*s mod 32 distinct

#define NCVT      2048                   // cvt blocks appended to prep grid
#define NI_F      (N_ROWS * C_IN / 8)    // 2,000,000 feats 8-elem chunks
#define NI_W      (K_VOL * C_IN * C_OUT) // 27,648 weight elems

typedef __attribute__((ext_vector_type(8))) short s16x8;   // 8 bf16
typedef __attribute__((ext_vector_type(4))) float f32x4;

static __device__ __forceinline__ unsigned short f2bf(float x) {
    union { float f; unsigned int u; } c; c.f = x;
    const unsigned int r = (c.u + 0x7FFFu + ((c.u >> 16) & 1u)) >> 16;
    return (unsigned short)r;
}
// pack 2 f32 -> 2 bf16 (RNE); dst.lo = bf16(lo), dst.hi = bf16(hi)
static __device__ __forceinline__ unsigned int cvtpk(float lo, float hi) {
    unsigned int r;
    asm("v_cvt_pk_bf16_f32 %0, %1, %2" : "=v"(r) : "v"(lo), "v"(hi));
    return r;
}
// af[d] accumulates (channel 2d, channel 2d+1) as f32 pair
static __device__ __forceinline__ void unpack_add(float2* af, const s16x8& f) {
    union { s16x8 v; unsigned int w[4]; } u; u.v = f;
#pragma unroll
    for (int d = 0; d < 4; ++d) {
        af[d].x += __uint_as_float(u.w[d] << 16);          // even channel
        af[d].y += __uint_as_float(u.w[d] & 0xffff0000u);  // odd channel
    }
}

// ---------------- Prep (merged): blocks 0..431 = counting sort; 432+ = cvt ----------------
// payload: irow(19) | lrow(4)<<19 | tile-in-region(5)<<23
__global__ __launch_bounds__(256) void prep_kernel(
    const float* __restrict__ feats, const float* __restrict__ weight,
    const int* __restrict__ in_idx, const int* __restrict__ out_idx,
    unsigned short* __restrict__ feats16, unsigned short* __restrict__ wT16,
    int* __restrict__ lstartG, unsigned int* __restrict__ edge_buf)
{
    __shared__ int lh[NREG];
    __shared__ int lstart[NREG + 1];
    __shared__ int lcur[NREG];
    __shared__ int partial[256];
    __shared__ unsigned int pay[CHUNK];          // 61 KB (75 KB total)
    const int bx = blockIdx.x, tid = threadIdx.x;

    if (bx >= NSEG) {
        // cvt region: feats fp32->bf16 + weight transpose
        const int id0 = (bx - NSEG) * 256 + tid;
        const int stride = NCVT * 256;
        for (int i = id0; i < NI_F; i += stride) {
            const float4 v0 = reinterpret_cast<const float4*>(feats)[i * 2];
            const float4 v1 = reinterpret_cast<const float4*>(feats)[i * 2 + 1];
            s16x8 r;
            r[0] = (short)f2bf(v0.x); r[1] = (short)f2bf(v0.y);
            r[2] = (short)f2bf(v0.z); r[3] = (short)f2bf(v0.w);
            r[4] = (short)f2bf(v1.x); r[5] = (short)f2bf(v1.y);
            r[6] = (short)f2bf(v1.z); r[7] = (short)f2bf(v1.w);
            *reinterpret_cast<s16x8*>(feats16 + (size_t)i * 8) = r;
        }
        if (id0 < NI_W) {
            const int k = id0 >> 10, rem = id0 & 1023;
            const int co = rem >> 5, ci = rem & 31;
            wT16[id0] = f2bf(weight[k * 1024 + ci * 32 + co]);
        }
        return;
    }

    // fill region (round-12-verified body)
    const int blk = bx & 15, k = bx >> 4;
    const int seg = k * BPB + blk;

    for (int r = tid; r < NREG; r += 256) lh[r] = 0;
    __syncthreads();

    const int eb0 = k * M_EDGE + blk * CHUNK;
    const int* ob = out_idx + eb0;
    const int* ib = in_idx + eb0;

    for (int t = tid; t < CHUNK; t += 256)
        atomicAdd(&lh[ob[t] >> 9], 1);           // region = row/512
    __syncthreads();

    int psum = 0;
    const int r0 = tid * 4;
#pragma unroll
    for (int j = 0; j < 4; ++j) { const int r = r0 + j; if (r < NREG) psum += lh[r]; }
    partial[tid] = psum;
    __syncthreads();
    for (int off = 1; off < 256; off <<= 1) {
        const int t = (tid >= off) ? partial[tid - off] : 0;
        __syncthreads();
        partial[tid] += t;
        __syncthreads();
    }
    int run = partial[tid] - psum;
#pragma unroll
    for (int j = 0; j < 4; ++j) {
        const int r = r0 + j;
        if (r < NREG) { lstart[r] = run; lcur[r] = run; run += lh[r]; }
    }
    if (tid == 0) lstart[NREG] = CHUNK;
    __syncthreads();

    for (int r = tid; r <= NREG; r += 256)
        lstartG[seg * OSTRIDE + r] = lstart[r];

    for (int t = tid; t < CHUNK; t += 256) {
        const int row = ob[t];
        const int irow = ib[t];
        const int idx = atomicAdd(&lcur[row >> 9], 1);
        pay[idx] = (unsigned int)irow | ((unsigned int)(row & 15) << 19) |
                   ((unsigned int)((row >> 4) & 31) << 23);
    }
    __syncthreads();

    unsigned int* dst = edge_buf + (size_t)seg * CHUNK;
    for (int q = tid; q < CHUNK; q += 256)
        dst[q] = pay[q];
}

// ---------------- Conv: round-15 core, software-pipelined (1 barrier/k) ----------------
// Phase k: bucket(k+1) into lists[(k+1)&1]/lcnt[(k+1)%3]  ||  compute(k) from
// lists[k&1]/lcnt[k%3]  ||  zero lcnt[(k+2)%3]; then ONE __syncthreads().
// Buffer disjointness: lcnt indices distinct mod 3; lists distinct mod 2; the
// overwrite of lists[k&1] by bucket(k+2) happens after the phase-k barrier.
__global__ __launch_bounds__(512, 4) void conv_mfma13(
    const unsigned short* __restrict__ feats16,
    const unsigned short* __restrict__ wT16,
    const int* __restrict__ lstartG,
    const unsigned int* __restrict__ edge_buf,
    float* __restrict__ out)
{
    __shared__ int lcnt[3 * NLISTS];                       // 6 KB (3-rotation)
    __shared__ unsigned int lists[2 * NLISTS * LSTRIDE];   // 69.6 KB (2-rotation)
    __shared__ int lsAll[NSEG * 2];                        // 3.4 KB
    const int g = blockIdx.x;
    const int tid = threadIdx.x;
    const int lane = tid & 63, wv = tid >> 6;
    const int slot = lane & 15, chunk = lane >> 4;

    // upfront: all (k,blk) bounds for region g; zero all lcnt buffers
    for (int i = tid; i < NSEG * 2; i += 512)
        lsAll[i] = lstartG[(i >> 1) * OSTRIDE + g + (i & 1)];
    lcnt[tid] = 0;
    lcnt[tid + NLISTS] = 0;
    lcnt[tid + 2 * NLISTS] = 0;

    f32x4 a0[4], a1[4];
#pragma unroll
    for (int j = 0; j < 4; ++j) {
        a0[j] = (f32x4){0.f, 0.f, 0.f, 0.f};
        a1[j] = (f32x4){0.f, 0.f, 0.f, 0.f};
    }
    __syncthreads();

    // prologue: bucket k=0 into lists[0]/lcnt[0]
    {
        const int bb = tid >> 5, u = tid & 31;
        const int sB = lsAll[bb * 2], eB = lsAll[bb * 2 + 1];
        const unsigned int* ebp = edge_buf + (size_t)bb * CHUNK;
        for (int t = sB + u; t < eB; t += 32) {
            const unsigned int p = ebp[t];
            const int li = (int)((p >> 19) & 0x1FFu);
            const int idx = atomicAdd(&lcnt[li], 1);
            if (idx < CAPL) lists[li * LSTRIDE + idx] = p & 0x7FFFFu;
        }
    }
    __syncthreads();

#pragma unroll 1
    for (int k = 0; k < K_VOL; ++k) {
        // ---- A) bucket k+1 (global loads issue first; latency hides under compute) ----
        if (k + 1 < K_VOL) {
            const int kn = k + 1;
            const int cbn = (kn % 3) * NLISTS;
            unsigned int* lstn = lists + (kn & 1) * (NLISTS * LSTRIDE);
            const int bb = tid >> 5, u = tid & 31;
            const int sB = lsAll[(kn * BPB + bb) * 2], eB = lsAll[(kn * BPB + bb) * 2 + 1];
            const unsigned int* ebp = edge_buf + (size_t)(kn * BPB + bb) * CHUNK;
            for (int t = sB + u; t < eB; t += 32) {
                const unsigned int p = ebp[t];
                const int li = (int)((p >> 19) & 0x1FFu);   // tile*16 + lrow
                const int idx = atomicAdd(&lcnt[cbn + li], 1);
                if (idx < CAPL) lstn[li * LSTRIDE + idx] = p & 0x7FFFFu;
            }
        }
        // zero the lcnt buffer for k+2 (last read by compute(k-1), one barrier ago)
        lcnt[((k + 2) % 3) * NLISTS + tid] = 0;

        // ---- B) compute k (round-15-verified body, reading buffers k%3 / k&1) ----
        const int cb = (k % 3) * NLISTS;
        const unsigned int* lst = lists + (k & 1) * (NLISTS * LSTRIDE);

        const unsigned short* wk = wT16 + k * (C_IN * C_OUT);
        const s16x8 b0 = *reinterpret_cast<const s16x8*>(wk + slot * 32 + chunk * 8);
        const s16x8 b1 = *reinterpret_cast<const s16x8*>(wk + (slot + 16) * 32 + chunk * 8);

        int myc[4]; unsigned int e0[4], e1[4], e2[4];
#pragma unroll
        for (int j = 0; j < 4; ++j) {
            const int li = (wv * 4 + j) * 16 + slot;
            const int c = lcnt[cb + li];
            myc[j] = c > CAPL ? CAPL : c;
            e0[j] = lst[li * LSTRIDE];          // stale-safe: gathers are masked
            e1[j] = lst[li * LSTRIDE + 1];
            e2[j] = lst[li * LSTRIDE + 2];
        }
        s16x8 g0[4], g1[4], g2[4];
#pragma unroll
        for (int j = 0; j < 4; ++j) {
            g0[j] = (s16x8){0, 0, 0, 0, 0, 0, 0, 0};
            g1[j] = (s16x8){0, 0, 0, 0, 0, 0, 0, 0};
            g2[j] = (s16x8){0, 0, 0, 0, 0, 0, 0, 0};
        }
#pragma unroll
        for (int j = 0; j < 4; ++j)
            if (0 < myc[j])
                g0[j] = *reinterpret_cast<const s16x8*>(
                    feats16 + (size_t)e0[j] * C_IN + chunk * 8);
#pragma unroll
        for (int j = 0; j < 4; ++j)
            if (1 < myc[j])
                g1[j] = *reinterpret_cast<const s16x8*>(
                    feats16 + (size_t)e1[j] * C_IN + chunk * 8);
#pragma unroll
        for (int j = 0; j < 4; ++j)
            if (2 < myc[j])
                g2[j] = *reinterpret_cast<const s16x8*>(
                    feats16 + (size_t)e2[j] * C_IN + chunk * 8);

#pragma unroll
        for (int j = 0; j < 4; ++j) {
            union { unsigned int w[4]; s16x8 v; } A;
            if (!__any(myc[j] > 1)) {
                A.v = g0[j];                    // bit-identical: cvtpk(bf2f(x)) == x
            } else {
                float2 af[4];
#pragma unroll
                for (int d = 0; d < 4; ++d) af[d] = make_float2(0.f, 0.f);
                unpack_add(af, g0[j]);
                unpack_add(af, g1[j]);
                unpack_add(af, g2[j]);
                const int li = (wv * 4 + j) * 16 + slot;
#pragma unroll 1
                for (int i = 3; __any(i < myc[j]); ++i) {     // rare tail (~2.8%)
                    s16x8 f = {0, 0, 0, 0, 0, 0, 0, 0};
                    if (i < myc[j])
                        f = *reinterpret_cast<const s16x8*>(
                            feats16 + (size_t)lst[li * LSTRIDE + i] * C_IN + chunk * 8);
                    unpack_add(af, f);
                }
#pragma unroll
                for (int d = 0; d < 4; ++d) A.w[d] = cvtpk(af[d].x, af[d].y);
            }
            a0[j] = __builtin_amdgcn_mfma_f32_16x16x32_bf16(A.v, b0, a0[j], 0, 0, 0);
            a1[j] = __builtin_amdgcn_mfma_f32_16x16x32_bf16(A.v, b1, a1[j], 0, 0, 0);
        }
        __syncthreads();                         // the ONE barrier per k
    }

    // D layout: col = lane&15, row = chunk*4 + jj
#pragma unroll
    for (int j = 0; j < 4; ++j) {
        const int rtg = g * 32 + wv * 4 + j;
        if (rtg < NT) {
            const int r0 = rtg * 16 + chunk * 4;
#pragma unroll
            for (int jj = 0; jj < 4; ++jj) {
                out[(size_t)(r0 + jj) * C_OUT + slot]      = a0[j][jj];
                out[(size_t)(r0 + jj) * C_OUT + 16 + slot] = a1[j][jj];
            }
        }
    }
}

// ---------------- Fallback (edge-atomic) if ws too small ----------------
__global__ __launch_bounds__(256) void spconv_edges(
    const float* __restrict__ feats, const float* __restrict__ weight,
    const int* __restrict__ in_idx, const int* __restrict__ out_idx,
    float* __restrict__ out)
{
    const int k = blockIdx.y;
    const int tid = threadIdx.x;
    const int g = tid >> 3, l = tid & 7, c0 = l * 4;
    const float* wk = weight + k * (C_IN * C_OUT);
    float4 wr[32];
#pragma unroll
    for (int ci = 0; ci < 32; ++ci)
        wr[ci] = *reinterpret_cast<const float4*>(wk + ci * C_OUT + c0);
    const int* ik = in_idx + k * M_EDGE;
    const int* ok = out_idx + k * M_EDGE;
    int m = blockIdx.x * 1024 + g;
#pragma unroll 1
    for (int it = 0; it < 32; ++it, m += 32) {
        if (m >= M_EDGE) break;
        const int irow = ik[m], orow = ok[m];
        const float4* frow =
            reinterpret_cast<const float4*>(feats + (size_t)irow * C_IN);
        float4 a = make_float4(0.f, 0.f, 0.f, 0.f);
#pragma unroll
        for (int j = 0; j < 8; ++j) {
            const float4 f4 = frow[j];
            const float fv[4] = {f4.x, f4.y, f4.z, f4.w};
#pragma unroll
            for (int t = 0; t < 4; ++t) {
                const float4 w4 = wr[j * 4 + t];
                a.x = fmaf(fv[t], w4.x, a.x);
                a.y = fmaf(fv[t], w4.y, a.y);
                a.z = fmaf(fv[t], w4.z, a.z);
                a.w = fmaf(fv[t], w4.w, a.w);
            }
        }
        float* op = out + (size_t)orow * C_OUT + c0;
        unsafeAtomicAdd(op + 0, a.x);
        unsafeAtomicAdd(op + 1, a.y);
        unsafeAtomicAdd(op + 2, a.z);
        unsafeAtomicAdd(op + 3, a.w);
    }
}

extern "C" void kernel_launch(void* const* d_in, const int* in_sizes, int n_in,
                              void* d_out, int out_size, void* d_ws, size_t ws_size,
                              hipStream_t stream) {
    const float* feats   = (const float*)d_in[0];
    const float* weight  = (const float*)d_in[1];
    const int*   in_idx  = (const int*)d_in[2];
    const int*   out_idx = (const int*)d_in[3];
    float*       out     = (float*)d_out;

    const size_t feats16_elems = (size_t)N_ROWS * C_IN;          // 16M ushort
    const size_t wT16_elems    = (size_t)K_VOL * C_IN * C_OUT;   // 27,648
    const size_t lstart_elems  = (size_t)NSEG * OSTRIDE;         // 422,496
    const size_t need_bytes = feats16_elems * 2 + wT16_elems * 2 +
        lstart_elems * sizeof(int) + (size_t)E_TOT * 4 + 256;    // ~60.7 MB

    if (ws_size >= need_bytes) {
        unsigned short* feats16 = (unsigned short*)d_ws;
        unsigned short* wT16    = feats16 + feats16_elems;
        int* lstartG = (int*)(wT16 + wT16_elems);               // NSEG*OSTRIDE
        unsigned int* edge_buf = (unsigned int*)(lstartG + lstart_elems);  // E_TOT

        prep_kernel<<<NSEG + NCVT, 256, 0, stream>>>(
            feats, weight, in_idx, out_idx, feats16, wT16, lstartG, edge_buf);
        conv_mfma13<<<NREG, 512, 0, stream>>>(feats16, wT16, lstartG, edge_buf, out);
    } else {
        hipMemsetAsync(out, 0, (size_t)out_size * sizeof(float), stream);
        dim3 grid((M_EDGE + 1023) / 1024, K_VOL);
        spconv_edges<<<grid, dim3(256), 0, stream>>>(feats, weight, in_idx, out_idx, out);
    }
}

// Round 17
// 250.991 us; speedup vs baseline: 1.0007x; 1.0007x over previous
//
#include <hip/hip_runtime.h>

#define C_IN   32
#define C_OUT  32
#define K_VOL  27
#define M_EDGE 250000
#define N_ROWS 500000
#define E_TOT  (K_VOL * M_EDGE)          // 6,750,000 edges

#define NT        (N_ROWS / 16)          // 31250 row-tiles of 16 rows
#define NREG      977                    // sort regions of 32 tiles (512 rows)
#define BPB       16                     // fill blocks per k
#define CHUNK     (M_EDGE / BPB)         // 15625 edges per (k,blk) segment
#define OSTRIDE   (NREG + 1)             // 978 offsets per segment
#define NSEG      (K_VOL * BPB)          // 432 private segments
#define NLISTS2   256                    // per-(tile,row) lists per half-region block
#define CAPL      16                     // list capacity: P(Pois(0.5)>16) ~ 1e-19
#define LSTRIDE   17                     // pad stride: 17*s mod 32 distinct

#define NCVT      2048                   // cvt blocks appended to prep grid
#define NI_F      (N_ROWS * C_IN / 8)    // 2,000,000 feats 8-elem chunks
#define NI_W      (K_VOL * C_IN * C_OUT) // 27,648 weight elems

typedef __attribute__((ext_vector_type(8))) short s16x8;   // 8 bf16
typedef __attribute__((ext_vector_type(4))) float f32x4;

static __device__ __forceinline__ unsigned short f2bf(float x) {
    union { float f; unsigned int u; } c; c.f = x;
    const unsigned int r = (c.u + 0x7FFFu + ((c.u >> 16) & 1u)) >> 16;
    return (unsigned short)r;
}
// pack 2 f32 -> 2 bf16 (RNE); dst.lo = bf16(lo), dst.hi = bf16(hi)
static __device__ __forceinline__ unsigned int cvtpk(float lo, float hi) {
    unsigned int r;
    asm("v_cvt_pk_bf16_f32 %0, %1, %2" : "=v"(r) : "v"(lo), "v"(hi));
    return r;
}
// af[d] accumulates (channel 2d, channel 2d+1) as f32 pair
static __device__ __forceinline__ void unpack_add(float2* af, const s16x8& f) {
    union { s16x8 v; unsigned int w[4]; } u; u.v = f;
#pragma unroll
    for (int d = 0; d < 4; ++d) {
        af[d].x += __uint_as_float(u.w[d] << 16);          // even channel
        af[d].y += __uint_as_float(u.w[d] & 0xffff0000u);  // odd channel
    }
}

// ---------------- Prep (merged): blocks 0..431 = counting sort; 432+ = cvt ----------------
// payload: irow(19) | lrow(4)<<19 | tile-in-region(5)<<23
__global__ __launch_bounds__(256) void prep_kernel(
    const float* __restrict__ feats, const float* __restrict__ weight,
    const int* __restrict__ in_idx, const int* __restrict__ out_idx,
    unsigned short* __restrict__ feats16, unsigned short* __restrict__ wT16,
    int* __restrict__ lstartG, unsigned int* __restrict__ edge_buf)
{
    __shared__ int lh[NREG];
    __shared__ int lstart[NREG + 1];
    __shared__ int lcur[NREG];
    __shared__ int partial[256];
    __shared__ unsigned int pay[CHUNK];          // 61 KB (75 KB total)
    const int bx = blockIdx.x, tid = threadIdx.x;

    if (bx >= NSEG) {
        // cvt region: feats fp32->bf16 + weight transpose
        const int id0 = (bx - NSEG) * 256 + tid;
        const int stride = NCVT * 256;
        for (int i = id0; i < NI_F; i += stride) {
            const float4 v0 = reinterpret_cast<const float4*>(feats)[i * 2];
            const float4 v1 = reinterpret_cast<const float4*>(feats)[i * 2 + 1];
            s16x8 r;
            r[0] = (short)f2bf(v0.x); r[1] = (short)f2bf(v0.y);
            r[2] = (short)f2bf(v0.z); r[3] = (short)f2bf(v0.w);
            r[4] = (short)f2bf(v1.x); r[5] = (short)f2bf(v1.y);
            r[6] = (short)f2bf(v1.z); r[7] = (short)f2bf(v1.w);
            *reinterpret_cast<s16x8*>(feats16 + (size_t)i * 8) = r;
        }
        if (id0 < NI_W) {
            const int k = id0 >> 10, rem = id0 & 1023;
            const int co = rem >> 5, ci = rem & 31;
            wT16[id0] = f2bf(weight[k * 1024 + ci * 32 + co]);
        }
        return;
    }

    // fill region (round-12-verified body)
    const int blk = bx & 15, k = bx >> 4;
    const int seg = k * BPB + blk;

    for (int r = tid; r < NREG; r += 256) lh[r] = 0;
    __syncthreads();

    const int eb0 = k * M_EDGE + blk * CHUNK;
    const int* ob = out_idx + eb0;
    const int* ib = in_idx + eb0;

    for (int t = tid; t < CHUNK; t += 256)
        atomicAdd(&lh[ob[t] >> 9], 1);           // region = row/512
    __syncthreads();

    int psum = 0;
    const int r0 = tid * 4;
#pragma unroll
    for (int j = 0; j < 4; ++j) { const int r = r0 + j; if (r < NREG) psum += lh[r]; }
    partial[tid] = psum;
    __syncthreads();
    for (int off = 1; off < 256; off <<= 1) {
        const int t = (tid >= off) ? partial[tid - off] : 0;
        __syncthreads();
        partial[tid] += t;
        __syncthreads();
    }
    int run = partial[tid] - psum;
#pragma unroll
    for (int j = 0; j < 4; ++j) {
        const int r = r0 + j;
        if (r < NREG) { lstart[r] = run; lcur[r] = run; run += lh[r]; }
    }
    if (tid == 0) lstart[NREG] = CHUNK;
    __syncthreads();

    for (int r = tid; r <= NREG; r += 256)
        lstartG[seg * OSTRIDE + r] = lstart[r];

    for (int t = tid; t < CHUNK; t += 256) {
        const int row = ob[t];
        const int irow = ib[t];
        const int idx = atomicAdd(&lcur[row >> 9], 1);
        pay[idx] = (unsigned int)irow | ((unsigned int)(row & 15) << 19) |
                   ((unsigned int)((row >> 4) & 31) << 23);
    }
    __syncthreads();

    unsigned int* dst = edge_buf + (size_t)seg * CHUNK;
    for (int q = tid; q < CHUNK; q += 256)
        dst[q] = pay[q];
}

// ---------------- Conv: half-region blocks (256 thr, ~7 blocks/CU), round-15 core ----------------
// Block = 16 tiles (half a sort-region, filter by payload tile-bit-4 — the
// round-10-verified mapping). 4 waves x 4 tiles. Body = round-15-verified:
// dbuf lcnt (2 barriers/k), depth-3 prefetch, fast path. (256,4): no spill.
__global__ __launch_bounds__(256, 4) void conv_mfma14(
    const unsigned short* __restrict__ feats16,
    const unsigned short* __restrict__ wT16,
    const int* __restrict__ lstartG,
    const unsigned int* __restrict__ edge_buf,
    float* __restrict__ out)
{
    __shared__ int lcnt[2 * NLISTS2];                   // double-buffered, 2 KB
    __shared__ unsigned int lists[NLISTS2 * LSTRIDE];   // 17.4 KB
    __shared__ int lsAll[NSEG * 2];                     // 3.4 KB
    const int g2 = blockIdx.x;          // 0..2*NREG-1
    const int g  = g2 >> 1;             // sort-region
    const int half = g2 & 1;            // which 16-tile half
    const int tid = threadIdx.x;
    const int lane = tid & 63, wv = tid >> 6;   // 4 waves
    const int slot = lane & 15, chunk = lane >> 4;

    // upfront: all (k,blk) bounds for region g
    for (int i = tid; i < NSEG * 2; i += 256)
        lsAll[i] = lstartG[(i >> 1) * OSTRIDE + g + (i & 1)];
    lcnt[tid] = 0;
    lcnt[tid + NLISTS2] = 0;

    f32x4 a0[4], a1[4];
#pragma unroll
    for (int j = 0; j < 4; ++j) {
        a0[j] = (f32x4){0.f, 0.f, 0.f, 0.f};
        a1[j] = (f32x4){0.f, 0.f, 0.f, 0.f};
    }
    __syncthreads();

#pragma unroll 1
    for (int k = 0; k < K_VOL; ++k) {
        const int cb = (k & 1) * NLISTS2;              // current lcnt buffer

        // bucket: 16 threads per sub-range (16 sub-ranges), filter by half
        const int bb = tid >> 4, u = tid & 15;
        const int sB = lsAll[(k * BPB + bb) * 2], eB = lsAll[(k * BPB + bb) * 2 + 1];
        const unsigned int* ebp = edge_buf + (size_t)(k * BPB + bb) * CHUNK;
        for (int t = sB + u; t < eB; t += 16) {
            const unsigned int p = ebp[t];
            if ((int)((p >> 27) & 1u) != half) continue;   // other half
            const int li = (int)((p >> 19) & 0xFFu);       // (tile&15)*16 + lrow
            const int idx = atomicAdd(&lcnt[cb + li], 1);
            if (idx < CAPL) lists[li * LSTRIDE + idx] = p & 0x7FFFFu;
        }
        __syncthreads();

        // clear the OTHER lcnt buffer for k+1 (two barriers from its last read)
        lcnt[(cb ^ NLISTS2) + tid] = 0;

        // W_k B-fragments: lane holds W[co=slot(+16)][ci=chunk*8..+7]
        const unsigned short* wk = wT16 + k * (C_IN * C_OUT);
        const s16x8 b0 = *reinterpret_cast<const s16x8*>(wk + slot * 32 + chunk * 8);
        const s16x8 b1 = *reinterpret_cast<const s16x8*>(wk + (slot + 16) * 32 + chunk * 8);

        // ---- counts + first three entries for all 4 tiles (conflict-free LDS) ----
        int myc[4]; unsigned int e0[4], e1[4], e2[4];
#pragma unroll
        for (int j = 0; j < 4; ++j) {
            const int li = (wv * 4 + j) * 16 + slot;
            const int c = lcnt[cb + li];
            myc[j] = c > CAPL ? CAPL : c;
            e0[j] = lists[li * LSTRIDE];        // stale-safe: gathers are masked
            e1[j] = lists[li * LSTRIDE + 1];
            e2[j] = lists[li * LSTRIDE + 2];
        }
        // ---- up to 12 independent gathers in flight (depth 3 x 4 tiles) ----
        s16x8 g0[4], g1[4], g2[4];
#pragma unroll
        for (int j = 0; j < 4; ++j) {
            g0[j] = (s16x8){0, 0, 0, 0, 0, 0, 0, 0};
            g1[j] = (s16x8){0, 0, 0, 0, 0, 0, 0, 0};
            g2[j] = (s16x8){0, 0, 0, 0, 0, 0, 0, 0};
        }
#pragma unroll
        for (int j = 0; j < 4; ++j)
            if (0 < myc[j])
                g0[j] = *reinterpret_cast<const s16x8*>(
                    feats16 + (size_t)e0[j] * C_IN + chunk * 8);
#pragma unroll
        for (int j = 0; j < 4; ++j)
            if (1 < myc[j])
                g1[j] = *reinterpret_cast<const s16x8*>(
                    feats16 + (size_t)e1[j] * C_IN + chunk * 8);
#pragma unroll
        for (int j = 0; j < 4; ++j)
            if (2 < myc[j])
                g2[j] = *reinterpret_cast<const s16x8*>(
                    feats16 + (size_t)e2[j] * C_IN + chunk * 8);

        // ---- per tile: fast path (all counts <=1) or unpack-sum path + MFMA ----
#pragma unroll
        for (int j = 0; j < 4; ++j) {
            union { unsigned int w[4]; s16x8 v; } A;
            if (!__any(myc[j] > 1)) {
                A.v = g0[j];                    // bit-identical: cvtpk(bf2f(x)) == x
            } else {
                float2 af[4];
#pragma unroll
                for (int d = 0; d < 4; ++d) af[d] = make_float2(0.f, 0.f);
                unpack_add(af, g0[j]);
                unpack_add(af, g1[j]);
                unpack_add(af, g2[j]);
                const int li = (wv * 4 + j) * 16 + slot;
#pragma unroll 1
                for (int i = 3; __any(i < myc[j]); ++i) {     // rare tail (~2.8%)
                    s16x8 f = {0, 0, 0, 0, 0, 0, 0, 0};
                    if (i < myc[j])
                        f = *reinterpret_cast<const s16x8*>(
                            feats16 + (size_t)lists[li * LSTRIDE + i] * C_IN + chunk * 8);
                    unpack_add(af, f);
                }
#pragma unroll
                for (int d = 0; d < 4; ++d) A.w[d] = cvtpk(af[d].x, af[d].y);
            }
            a0[j] = __builtin_amdgcn_mfma_f32_16x16x32_bf16(A.v, b0, a0[j], 0, 0, 0);
            a1[j] = __builtin_amdgcn_mfma_f32_16x16x32_bf16(A.v, b1, a1[j], 0, 0, 0);
        }
        __syncthreads();
    }

    // D layout: col = lane&15, row = chunk*4 + jj
#pragma unroll
    for (int j = 0; j < 4; ++j) {
        const int rtg = g * 32 + half * 16 + wv * 4 + j;
        if (rtg < NT) {
            const int r0 = rtg * 16 + chunk * 4;
#pragma unroll
            for (int jj = 0; jj < 4; ++jj) {
                out[(size_t)(r0 + jj) * C_OUT + slot]      = a0[j][jj];
                out[(size_t)(r0 + jj) * C_OUT + 16 + slot] = a1[j][jj];
            }
        }
    }
}

// ---------------- Fallback (edge-atomic) if ws too small ----------------
__global__ __launch_bounds__(256) void spconv_edges(
    const float* __restrict__ feats, const float* __restrict__ weight,
    const int* __restrict__ in_idx, const int* __restrict__ out_idx,
    float* __restrict__ out)
{
    const int k = blockIdx.y;
    const int tid = threadIdx.x;
    const int g = tid >> 3, l = tid & 7, c0 = l * 4;
    const float* wk = weight + k * (C_IN * C_OUT);
    float4 wr[32];
#pragma unroll
    for (int ci = 0; ci < 32; ++ci)
        wr[ci] = *reinterpret_cast<const float4*>(wk + ci * C_OUT + c0);
    const int* ik = in_idx + k * M_EDGE;
    const int* ok = out_idx + k * M_EDGE;
    int m = blockIdx.x * 1024 + g;
#pragma unroll 1
    for (int it = 0; it < 32; ++it, m += 32) {
        if (m >= M_EDGE) break;
        const int irow = ik[m], orow = ok[m];
        const float4* frow =
            reinterpret_cast<const float4*>(feats + (size_t)irow * C_IN);
        float4 a = make_float4(0.f, 0.f, 0.f, 0.f);
#pragma unroll
        for (int j = 0; j < 8; ++j) {
            const float4 f4 = frow[j];
            const float fv[4] = {f4.x, f4.y, f4.z, f4.w};
#pragma unroll
            for (int t = 0; t < 4; ++t) {
                const float4 w4 = wr[j * 4 + t];
                a.x = fmaf(fv[t], w4.x, a.x);
                a.y = fmaf(fv[t], w4.y, a.y);
                a.z = fmaf(fv[t], w4.z, a.z);
                a.w = fmaf(fv[t], w4.w, a.w);
            }
        }
        float* op = out + (size_t)orow * C_OUT + c0;
        unsafeAtomicAdd(op + 0, a.x);
        unsafeAtomicAdd(op + 1, a.y);
        unsafeAtomicAdd(op + 2, a.z);
        unsafeAtomicAdd(op + 3, a.w);
    }
}

extern "C" void kernel_launch(void* const* d_in, const int* in_sizes, int n_in,
                              void* d_out, int out_size, void* d_ws, size_t ws_size,
                              hipStream_t stream) {
    const float* feats   = (const float*)d_in[0];
    const float* weight  = (const float*)d_in[1];
    const int*   in_idx  = (const int*)d_in[2];
    const int*   out_idx = (const int*)d_in[3];
    float*       out     = (float*)d_out;

    const size_t feats16_elems = (size_t)N_ROWS * C_IN;          // 16M ushort
    const size_t wT16_elems    = (size_t)K_VOL * C_IN * C_OUT;   // 27,648
    const size_t lstart_elems  = (size_t)NSEG * OSTRIDE;         // 422,496
    const size_t need_bytes = feats16_elems * 2 + wT16_elems * 2 +
        lstart_elems * sizeof(int) + (size_t)E_TOT * 4 + 256;    // ~60.7 MB

    if (ws_size >= need_bytes) {
        unsigned short* feats16 = (unsigned short*)d_ws;
        unsigned short* wT16    = feats16 + feats16_elems;
        int* lstartG = (int*)(wT16 + wT16_elems);               // NSEG*OSTRIDE
        unsigned int* edge_buf = (unsigned int*)(lstartG + lstart_elems);  // E_TOT

        prep_kernel<<<NSEG + NCVT, 256, 0, stream>>>(
            feats, weight, in_idx, out_idx, feats16, wT16, lstartG, edge_buf);
        conv_mfma14<<<NREG * 2, 256, 0, stream>>>(feats16, wT16, lstartG, edge_buf, out);
    } else {
        hipMemsetAsync(out, 0, (size_t)out_size * sizeof(float), stream);
        dim3 grid((M_EDGE + 1023) / 1024, K_VOL);
        spconv_edges<<<grid, dim3(256), 0, stream>>>(feats, weight, in_idx, out_idx, out);
    }
}

// Round 18
// 242.043 us; speedup vs baseline: 1.0376x; 1.0370x over previous
//
#include <hip/hip_runtime.h>

#define C_IN   32
#define C_OUT  32
#define K_VOL  27
#define M_EDGE 250000
#define N_ROWS 500000
#define E_TOT  (K_VOL * M_EDGE)          // 6,750,000 edges

#define NT        (N_ROWS / 16)          // 31250 row-tiles of 16 rows
#define NREG      977                    // sort regions of 32 tiles (512 rows)
#define BPB       16                     // fill blocks per k
#define CHUNK     (M_EDGE / BPB)         // 15625 edges per (k,blk) segment
#define OSTRIDE   (NREG + 1)             // 978 offsets per segment
#define NSEG      (K_VOL * BPB)          // 432 private segments
#define NLISTS    512                    // per-(tile,row) lists in conv
#define CAPL      16                     // list capacity: P(Pois(0.5)>16) ~ 1e-19
#define LSTRIDE   17                     // pad stride: 17*s mod 32 distinct

#define NCVT      2048                   // cvt blocks appended to prep grid
#define NI_F      (N_ROWS * C_IN / 8)    // 2,000,000 feats 8-elem chunks
#define NI_W      (K_VOL * C_IN * C_OUT) // 27,648 weight elems

typedef __attribute__((ext_vector_type(8))) short s16x8;   // 8 bf16
typedef __attribute__((ext_vector_type(4))) float f32x4;

static __device__ __forceinline__ unsigned short f2bf(float x) {
    union { float f; unsigned int u; } c; c.f = x;
    const unsigned int r = (c.u + 0x7FFFu + ((c.u >> 16) & 1u)) >> 16;
    return (unsigned short)r;
}
// pack 2 f32 -> 2 bf16 (RNE); dst.lo = bf16(lo), dst.hi = bf16(hi)
static __device__ __forceinline__ unsigned int cvtpk(float lo, float hi) {
    unsigned int r;
    asm("v_cvt_pk_bf16_f32 %0, %1, %2" : "=v"(r) : "v"(lo), "v"(hi));
    return r;
}
// af[d] accumulates (channel 2d, channel 2d+1) as f32 pair
static __device__ __forceinline__ void unpack_add(float2* af, const s16x8& f) {
    union { s16x8 v; unsigned int w[4]; } u; u.v = f;
#pragma unroll
    for (int d = 0; d < 4; ++d) {
        af[d].x += __uint_as_float(u.w[d] << 16);          // even channel
        af[d].y += __uint_as_float(u.w[d] & 0xffff0000u);  // odd channel
    }
}

// ---------------- Prep (merged): blocks 0..431 = counting sort; 432+ = cvt ----------------
// payload: irow(19) | lrow(4)<<19 | tile-in-region(5)<<23
__global__ __launch_bounds__(256) void prep_kernel(
    const float* __restrict__ feats, const float* __restrict__ weight,
    const int* __restrict__ in_idx, const int* __restrict__ out_idx,
    unsigned short* __restrict__ feats16, unsigned short* __restrict__ wT16,
    int* __restrict__ lstartG, unsigned int* __restrict__ edge_buf)
{
    __shared__ int lh[NREG];
    __shared__ int lstart[NREG + 1];
    __shared__ int lcur[NREG];
    __shared__ int partial[256];
    __shared__ unsigned int pay[CHUNK];          // 61 KB (75 KB total)
    const int bx = blockIdx.x, tid = threadIdx.x;

    if (bx >= NSEG) {
        // cvt region: feats fp32->bf16 + weight transpose
        const int id0 = (bx - NSEG) * 256 + tid;
        const int stride = NCVT * 256;
        for (int i = id0; i < NI_F; i += stride) {
            const float4 v0 = reinterpret_cast<const float4*>(feats)[i * 2];
            const float4 v1 = reinterpret_cast<const float4*>(feats)[i * 2 + 1];
            s16x8 r;
            r[0] = (short)f2bf(v0.x); r[1] = (short)f2bf(v0.y);
            r[2] = (short)f2bf(v0.z); r[3] = (short)f2bf(v0.w);
            r[4] = (short)f2bf(v1.x); r[5] = (short)f2bf(v1.y);
            r[6] = (short)f2bf(v1.z); r[7] = (short)f2bf(v1.w);
            *reinterpret_cast<s16x8*>(feats16 + (size_t)i * 8) = r;
        }
        if (id0 < NI_W) {
            const int k = id0 >> 10, rem = id0 & 1023;
            const int co = rem >> 5, ci = rem & 31;
            wT16[id0] = f2bf(weight[k * 1024 + ci * 32 + co]);
        }
        return;
    }

    // fill region (round-12-verified body)
    const int blk = bx & 15, k = bx >> 4;
    const int seg = k * BPB + blk;

    for (int r = tid; r < NREG; r += 256) lh[r] = 0;
    __syncthreads();

    const int eb0 = k * M_EDGE + blk * CHUNK;
    const int* ob = out_idx + eb0;
    const int* ib = in_idx + eb0;

    for (int t = tid; t < CHUNK; t += 256)
        atomicAdd(&lh[ob[t] >> 9], 1);           // region = row/512
    __syncthreads();

    int psum = 0;
    const int r0 = tid * 4;
#pragma unroll
    for (int j = 0; j < 4; ++j) { const int r = r0 + j; if (r < NREG) psum += lh[r]; }
    partial[tid] = psum;
    __syncthreads();
    for (int off = 1; off < 256; off <<= 1) {
        const int t = (tid >= off) ? partial[tid - off] : 0;
        __syncthreads();
        partial[tid] += t;
        __syncthreads();
    }
    int run = partial[tid] - psum;
#pragma unroll
    for (int j = 0; j < 4; ++j) {
        const int r = r0 + j;
        if (r < NREG) { lstart[r] = run; lcur[r] = run; run += lh[r]; }
    }
    if (tid == 0) lstart[NREG] = CHUNK;
    __syncthreads();

    for (int r = tid; r <= NREG; r += 256)
        lstartG[seg * OSTRIDE + r] = lstart[r];

    for (int t = tid; t < CHUNK; t += 256) {
        const int row = ob[t];
        const int irow = ib[t];
        const int idx = atomicAdd(&lcur[row >> 9], 1);
        pay[idx] = (unsigned int)irow | ((unsigned int)(row & 15) << 19) |
                   ((unsigned int)((row >> 4) & 31) << 23);
    }
    __syncthreads();

    unsigned int* dst = edge_buf + (size_t)seg * CHUNK;
    for (int q = tid; q < CHUNK; q += 256)
        dst[q] = pay[q];
}

// ---------------- Conv: verified best — dbuf lcnt (2 barriers/k) + depth-3 + fast path ----------------
__global__ __launch_bounds__(512, 4) void conv_mfma12(
    const unsigned short* __restrict__ feats16,
    const unsigned short* __restrict__ wT16,
    const int* __restrict__ lstartG,
    const unsigned int* __restrict__ edge_buf,
    float* __restrict__ out)
{
    __shared__ int lcnt[2 * NLISTS];                   // double-buffered, 4 KB
    __shared__ unsigned int lists[NLISTS * LSTRIDE];   // 34.8 KB
    __shared__ int lsAll[NSEG * 2];                    // 3.4 KB
    const int g = blockIdx.x;
    const int tid = threadIdx.x;
    const int lane = tid & 63, wv = tid >> 6;
    const int slot = lane & 15, chunk = lane >> 4;

    // upfront: all (k,blk) bounds for region g
    for (int i = tid; i < NSEG * 2; i += 512)
        lsAll[i] = lstartG[(i >> 1) * OSTRIDE + g + (i & 1)];
    lcnt[tid] = 0;
    lcnt[tid + NLISTS] = 0;

    f32x4 a0[4], a1[4];
#pragma unroll
    for (int j = 0; j < 4; ++j) {
        a0[j] = (f32x4){0.f, 0.f, 0.f, 0.f};
        a1[j] = (f32x4){0.f, 0.f, 0.f, 0.f};
    }
    __syncthreads();

#pragma unroll 1
    for (int k = 0; k < K_VOL; ++k) {
        const int cb = (k & 1) * NLISTS;               // current lcnt buffer

        // bucket: 32 threads per sub-range (16 sub-ranges, ~16 edges each)
        const int bb = tid >> 5, u = tid & 31;
        const int sB = lsAll[(k * BPB + bb) * 2], eB = lsAll[(k * BPB + bb) * 2 + 1];
        const unsigned int* ebp = edge_buf + (size_t)(k * BPB + bb) * CHUNK;
        for (int t = sB + u; t < eB; t += 32) {
            const unsigned int p = ebp[t];
            const int li = (int)((p >> 19) & 0x1FFu);   // tile*16 + lrow
            const int idx = atomicAdd(&lcnt[cb + li], 1);
            if (idx < CAPL) lists[li * LSTRIDE + idx] = p & 0x7FFFFu;
        }
        __syncthreads();

        // clear the OTHER lcnt buffer for k+1 (last read at compute(k-1),
        // separated from here by two barriers -> race-free)
        lcnt[(cb ^ NLISTS) + tid] = 0;

        // W_k B-fragments: lane holds W[co=slot(+16)][ci=chunk*8..+7]
        const unsigned short* wk = wT16 + k * (C_IN * C_OUT);
        const s16x8 b0 = *reinterpret_cast<const s16x8*>(wk + slot * 32 + chunk * 8);
        const s16x8 b1 = *reinterpret_cast<const s16x8*>(wk + (slot + 16) * 32 + chunk * 8);

        // ---- counts + first three entries for all 4 tiles (conflict-free LDS) ----
        int myc[4]; unsigned int e0[4], e1[4], e2[4];
#pragma unroll
        for (int j = 0; j < 4; ++j) {
            const int li = (wv * 4 + j) * 16 + slot;
            const int c = lcnt[cb + li];
            myc[j] = c > CAPL ? CAPL : c;
            e0[j] = lists[li * LSTRIDE];        // stale-safe: gathers are masked
            e1[j] = lists[li * LSTRIDE + 1];
            e2[j] = lists[li * LSTRIDE + 2];
        }
        // ---- up to 12 independent gathers in flight (depth 3 x 4 tiles) ----
        s16x8 g0[4], g1[4], g2[4];
#pragma unroll
        for (int j = 0; j < 4; ++j) {
            g0[j] = (s16x8){0, 0, 0, 0, 0, 0, 0, 0};
            g1[j] = (s16x8){0, 0, 0, 0, 0, 0, 0, 0};
            g2[j] = (s16x8){0, 0, 0, 0, 0, 0, 0, 0};
        }
#pragma unroll
        for (int j = 0; j < 4; ++j)
            if (0 < myc[j])
                g0[j] = *reinterpret_cast<const s16x8*>(
                    feats16 + (size_t)e0[j] * C_IN + chunk * 8);
#pragma unroll
        for (int j = 0; j < 4; ++j)
            if (1 < myc[j])
                g1[j] = *reinterpret_cast<const s16x8*>(
                    feats16 + (size_t)e1[j] * C_IN + chunk * 8);
#pragma unroll
        for (int j = 0; j < 4; ++j)
            if (2 < myc[j])
                g2[j] = *reinterpret_cast<const s16x8*>(
                    feats16 + (size_t)e2[j] * C_IN + chunk * 8);

        // ---- per tile: fast path (all counts <=1) or unpack-sum path + MFMA ----
#pragma unroll
        for (int j = 0; j < 4; ++j) {
            union { unsigned int w[4]; s16x8 v; } A;
            if (!__any(myc[j] > 1)) {
                A.v = g0[j];                    // bit-identical: cvtpk(bf2f(x)) == x
            } else {
                float2 af[4];
#pragma unroll
                for (int d = 0; d < 4; ++d) af[d] = make_float2(0.f, 0.f);
                unpack_add(af, g0[j]);
                unpack_add(af, g1[j]);
                unpack_add(af, g2[j]);
                const int li = (wv * 4 + j) * 16 + slot;
#pragma unroll 1
                for (int i = 3; __any(i < myc[j]); ++i) {     // rare tail (~2.8%)
                    s16x8 f = {0, 0, 0, 0, 0, 0, 0, 0};
                    if (i < myc[j])
                        f = *reinterpret_cast<const s16x8*>(
                            feats16 + (size_t)lists[li * LSTRIDE + i] * C_IN + chunk * 8);
                    unpack_add(af, f);
                }
#pragma unroll
                for (int d = 0; d < 4; ++d) A.w[d] = cvtpk(af[d].x, af[d].y);
            }
            a0[j] = __builtin_amdgcn_mfma_f32_16x16x32_bf16(A.v, b0, a0[j], 0, 0, 0);
            a1[j] = __builtin_amdgcn_mfma_f32_16x16x32_bf16(A.v, b1, a1[j], 0, 0, 0);
        }
        __syncthreads();
    }

    // D layout: col = lane&15, row = chunk*4 + jj
#pragma unroll
    for (int j = 0; j < 4; ++j) {
        const int rtg = g * 32 + wv * 4 + j;
        if (rtg < NT) {
            const int r0 = rtg * 16 + chunk * 4;
#pragma unroll
            for (int jj = 0; jj < 4; ++jj) {
                out[(size_t)(r0 + jj) * C_OUT + slot]      = a0[j][jj];
                out[(size_t)(r0 + jj) * C_OUT + 16 + slot] = a1[j][jj];
            }
        }
    }
}

// ---------------- Fallback (edge-atomic) if ws too small ----------------
__global__ __launch_bounds__(256) void spconv_edges(
    const float* __restrict__ feats, const float* __restrict__ weight,
    const int* __restrict__ in_idx, const int* __restrict__ out_idx,
    float* __restrict__ out)
{
    const int k = blockIdx.y;
    const int tid = threadIdx.x;
    const int g = tid >> 3, l = tid & 7, c0 = l * 4;
    const float* wk = weight + k * (C_IN * C_OUT);
    float4 wr[32];
#pragma unroll
    for (int ci = 0; ci < 32; ++ci)
        wr[ci] = *reinterpret_cast<const float4*>(wk + ci * C_OUT + c0);
    const int* ik = in_idx + k * M_EDGE;
    const int* ok = out_idx + k * M_EDGE;
    int m = blockIdx.x * 1024 + g;
#pragma unroll 1
    for (int it = 0; it < 32; ++it, m += 32) {
        if (m >= M_EDGE) break;
        const int irow = ik[m], orow = ok[m];
        const float4* frow =
            reinterpret_cast<const float4*>(feats + (size_t)irow * C_IN);
        float4 a = make_float4(0.f, 0.f, 0.f, 0.f);
#pragma unroll
        for (int j = 0; j < 8; ++j) {
            const float4 f4 = frow[j];
            const float fv[4] = {f4.x, f4.y, f4.z, f4.w};
#pragma unroll
            for (int t = 0; t < 4; ++t) {
                const float4 w4 = wr[j * 4 + t];
                a.x = fmaf(fv[t], w4.x, a.x);
                a.y = fmaf(fv[t], w4.y, a.y);
                a.z = fmaf(fv[t], w4.z, a.z);
                a.w = fmaf(fv[t], w4.w, a.w);
            }
        }
        float* op = out + (size_t)orow * C_OUT + c0;
        unsafeAtomicAdd(op + 0, a.x);
        unsafeAtomicAdd(op + 1, a.y);
        unsafeAtomicAdd(op + 2, a.z);
        unsafeAtomicAdd(op + 3, a.w);
    }
}

extern "C" void kernel_launch(void* const* d_in, const int* in_sizes, int n_in,
                              void* d_out, int out_size, void* d_ws, size_t ws_size,
                              hipStream_t stream) {
    const float* feats   = (const float*)d_in[0];
    const float* weight  = (const float*)d_in[1];
    const int*   in_idx  = (const int*)d_in[2];
    const int*   out_idx = (const int*)d_in[3];
    float*       out     = (float*)d_out;

    const size_t feats16_elems = (size_t)N_ROWS * C_IN;          // 16M ushort
    const size_t wT16_elems    = (size_t)K_VOL * C_IN * C_OUT;   // 27,648
    const size_t lstart_elems  = (size_t)NSEG * OSTRIDE;         // 422,496
    const size_t need_bytes = feats16_elems * 2 + wT16_elems * 2 +
        lstart_elems * sizeof(int) + (size_t)E_TOT * 4 + 256;    // ~60.7 MB

    if (ws_size >= need_bytes) {
        unsigned short* feats16 = (unsigned short*)d_ws;
        unsigned short* wT16    = feats16 + feats16_elems;
        int* lstartG = (int*)(wT16 + wT16_elems);               // NSEG*OSTRIDE
        unsigned int* edge_buf = (unsigned int*)(lstartG + lstart_elems);  // E_TOT

        prep_kernel<<<NSEG + NCVT, 256, 0, stream>>>(
            feats, weight, in_idx, out_idx, feats16, wT16, lstartG, edge_buf);
        conv_mfma12<<<NREG, 512, 0, stream>>>(feats16, wT16, lstartG, edge_buf, out);
    } else {
        hipMemsetAsync(out, 0, (size_t)out_size * sizeof(float), stream);
        dim3 grid((M_EDGE + 1023) / 1024, K_VOL);
        spconv_edges<<<grid, dim3(256), 0, stream>>>(feats, weight, in_idx, out_idx, out);
    }
}